// Round 2
// baseline (38.423 us; speedup 1.0000x reference)
//
#include <hip/hip_runtime.h>
#include <hip/hip_bf16.h>

typedef __attribute__((ext_vector_type(8))) short short8;
typedef __attribute__((ext_vector_type(4))) float floatx4;
typedef unsigned int u32;
typedef unsigned short u16;

#define NB 1024
#define ND 16
#define NM 4
#define NR 4096
#define NC 64
#define EPSF 1e-9f
#define KSPLIT 8

__device__ inline u16 f2bf(float f) {
    u32 u;
    __builtin_memcpy(&u, &f, 4);
    u32 lsb = (u >> 16) & 1;
    u += 0x7fffu + lsb;   // round-to-nearest-even
    return (u16)(u >> 16);
}

__device__ inline void gload16(u16* lds, const u16* g) {
    __builtin_amdgcn_global_load_lds((const __attribute__((address_space(1))) u32*)g,
                                     (__attribute__((address_space(3))) u32*)lds, 16, 0, 0);
}

// ---- Kernel A: s_consT[c][r] = bf16(sum_j cons[r,j,c]); pack rules (2b x 16d) ----
__global__ __launch_bounds__(256) void k_prep(const float* __restrict__ cons,
                                              const int* __restrict__ rules,
                                              u16* __restrict__ s_consT,
                                              u32* __restrict__ packed) {
    __shared__ u16 tile[64][72];  // [r_local][c], padded
    int rbase = blockIdx.x * 64;
    int tid = threadIdx.x;
    int c = tid & 63;
#pragma unroll
    for (int rr = tid >> 6; rr < 64; rr += 4) {
        int r = rbase + rr;
        const float* p = cons + (size_t)r * (ND + 1) * NC + c;
        float s = 0.f;
#pragma unroll
        for (int j = 0; j < ND + 1; ++j) s += p[j * NC];
        tile[rr][c] = f2bf(s);
    }
    if (tid < 64) {
        const int* q = rules + (size_t)(rbase + tid) * ND;
        u32 pk = 0;
#pragma unroll
        for (int d = 0; d < ND; ++d) pk |= ((u32)(q[d] & 3)) << (2 * d);
        packed[rbase + tid] = pk;
    }
    __syncthreads();
#pragma unroll
    for (int pass = 0; pass < 2; ++pass) {
        int cc = pass * 32 + (tid >> 3);
        int r0 = (tid & 7) * 8;
        short8 v;
#pragma unroll
        for (int e = 0; e < 8; ++e) v[e] = (short)tile[r0 + e][cc];
        *(short8*)(s_consT + (size_t)cc * NR + rbase + r0) = v;
    }
}

// ---- Kernel B: per-b firing strengths + normalization; fp32 nfs out + bf16 copy ----
__global__ __launch_bounds__(256) void k_fs(const float* __restrict__ x,
                                            const float* __restrict__ centers,
                                            const float* __restrict__ widths,
                                            const u32* __restrict__ packed,
                                            float* __restrict__ out_nfs,
                                            u16* __restrict__ nfs_bf,
                                            float* __restrict__ out_xe,
                                            float* __restrict__ sx) {
    __shared__ float xv[16];
    __shared__ float mftab[64];
    __shared__ float gtab[1024];
    __shared__ float fsbuf[4096];
    __shared__ float wred[4];
    __shared__ float s_inv;
    int b = blockIdx.x;
    int tid = threadIdx.x;
    if (tid < 16) {
        float raw = x[b * 16 + tid];
        xv[tid] = raw;
        out_xe[b * 17 + tid] = raw;
    }
    if (tid == 16) out_xe[b * 17 + 16] = 1.0f;
    __syncthreads();
    if (tid < 64) {
        float diff = xv[tid >> 2] - centers[tid];
        float w = widths[tid];
        mftab[tid] = __expf(-diff * diff / (2.f * w * w)) + EPSF;
    }
    if (tid == 0) {
        float s = 1.f;
        for (int i = 0; i < 16; ++i) s += xv[i];
        sx[b] = s;
    }
    __syncthreads();
    // 4 groups of 4 dims, 256-entry product tables
    for (int idx = tid; idx < 1024; idx += 256) {
        int g = idx >> 8, i = idx & 255;
        const float* mf = mftab + g * 16;
        gtab[idx] = mf[0 + (i & 3)] * mf[4 + ((i >> 2) & 3)] *
                    mf[8 + ((i >> 4) & 3)] * mf[12 + ((i >> 6) & 3)];
    }
    __syncthreads();
    float lsum = 0.f;
    for (int r = tid; r < NR; r += 256) {
        u32 p = packed[r];
        float f = gtab[p & 255] * gtab[256 + ((p >> 8) & 255)] *
                  gtab[512 + ((p >> 16) & 255)] * gtab[768 + (p >> 24)];
        fsbuf[r] = f;
        lsum += f;
    }
    for (int off = 32; off; off >>= 1) lsum += __shfl_down(lsum, off, 64);
    if ((tid & 63) == 0) wred[tid >> 6] = lsum;
    __syncthreads();
    if (tid == 0) s_inv = 1.f / (wred[0] + wred[1] + wred[2] + wred[3] + EPSF);
    __syncthreads();
    float inv = s_inv;
    float* on = out_nfs + (size_t)b * NR;
    u16* ob = nfs_bf + (size_t)b * NR;
    for (int r = tid; r < NR; r += 256) {
        float v = fsbuf[r] * inv;
        on[r] = v;
        ob[r] = f2bf(v);
    }
}

// ---- Kernel C: nfs_bf (B x R) @ s_cons (R x C) with K-split, MFMA bf16 ----
__global__ __launch_bounds__(256) void k_gemm(const u16* __restrict__ nfs,
                                              const u16* __restrict__ s_consT,
                                              float* __restrict__ part) {
    __shared__ __align__(16) u16 Abuf[2][128 * 32];
    __shared__ __align__(16) u16 Bbuf[2][64 * 32];
    int rt = blockIdx.x;  // row tile (128 rows)
    int ks = blockIdx.y;  // k split (512 k)
    int tid = threadIdx.x;
    int wid = tid >> 6, lane = tid & 63;
    int rowbase = rt * 128;
    int kbase0 = ks * (NR / KSPLIT);
    floatx4 acc[2][4] = {};

    auto stage = [&](int buf, int kb) {
#pragma unroll
        for (int q = 0; q < 2; ++q) {
            int chunk = wid * 2 + q;
            int row = rowbase + chunk * 16 + (lane >> 2);
            const u16* g = nfs + (size_t)row * NR + kb + (lane & 3) * 8;
            gload16(&Abuf[buf][chunk * 512 + lane * 8], g);
        }
        int c = wid * 16 + (lane >> 2);
        const u16* g = s_consT + (size_t)c * NR + kb + (lane & 3) * 8;
        gload16(&Bbuf[buf][wid * 512 + lane * 8], g);
    };

    stage(0, kbase0);
    asm volatile("s_waitcnt vmcnt(0)" ::: "memory");
    __syncthreads();
    int cur = 0;
    const int NT = (NR / KSPLIT) / 32;  // 16
    for (int t = 0; t < NT; ++t) {
        if (t + 1 < NT) stage(cur ^ 1, kbase0 + (t + 1) * 32);
        short8 af[2], bfv[4];
#pragma unroll
        for (int rb = 0; rb < 2; ++rb)
            af[rb] = *(const short8*)&Abuf[cur][(wid * 32 + rb * 16 + (lane & 15)) * 32 + (lane >> 4) * 8];
#pragma unroll
        for (int cb = 0; cb < 4; ++cb)
            bfv[cb] = *(const short8*)&Bbuf[cur][(cb * 16 + (lane & 15)) * 32 + (lane >> 4) * 8];
#pragma unroll
        for (int rb = 0; rb < 2; ++rb)
#pragma unroll
            for (int cb = 0; cb < 4; ++cb)
                acc[rb][cb] = __builtin_amdgcn_mfma_f32_16x16x32_bf16(af[rb], bfv[cb], acc[rb][cb], 0, 0, 0);
        asm volatile("s_waitcnt vmcnt(0)" ::: "memory");
        __syncthreads();
        cur ^= 1;
    }
#pragma unroll
    for (int rb = 0; rb < 2; ++rb)
#pragma unroll
        for (int cb = 0; cb < 4; ++cb)
#pragma unroll
            for (int reg = 0; reg < 4; ++reg) {
                int row = rowbase + wid * 32 + rb * 16 + (lane >> 4) * 4 + reg;
                int col = cb * 16 + (lane & 15);
                part[(size_t)ks * (NB * NC) + (size_t)row * NC + col] = acc[rb][cb][reg];
            }
}

// ---- Kernel D: reduce K-splits, scale by s_x, emit fp32 ----
__global__ __launch_bounds__(256) void k_out(const float* __restrict__ part,
                                             const float* __restrict__ sx,
                                             float* __restrict__ out0) {
    int t = blockIdx.x * 256 + threadIdx.x;
    if (t >= NB * NC) return;
    float a = 0.f;
#pragma unroll
    for (int ks = 0; ks < KSPLIT; ++ks) a += part[(size_t)ks * (NB * NC) + t];
    out0[t] = a * sx[t >> 6];
}

extern "C" void kernel_launch(void* const* d_in, const int* in_sizes, int n_in,
                              void* d_out, int out_size, void* d_ws, size_t ws_size,
                              hipStream_t stream) {
    const float* x = (const float*)d_in[0];
    const float* centers = (const float*)d_in[1];
    const float* widths = (const float*)d_in[2];
    const float* cons = (const float*)d_in[3];
    const int* rules = (const int*)d_in[4];

    float* out = (float*)d_out;
    float* out_rule = out;                        // [1024,64]
    float* out_nfs = out + NB * NC;               // [1024,4096]
    float* out_xe = out + NB * NC + NB * NR;      // [1024,17]

    char* ws = (char*)d_ws;
    u16* s_consT = (u16*)ws;                                   // 512 KB
    u32* packed = (u32*)(ws + (512 << 10));                    // 16 KB
    float* sx = (float*)(ws + (512 << 10) + (16 << 10));       // 4 KB
    float* part = (float*)(ws + (512 << 10) + (20 << 10));     // 2 MB
    u16* nfs_bf = (u16*)(ws + (512 << 10) + (20 << 10) + (NB * NC * KSPLIT * 4));  // 8 MB

    k_prep<<<NR / 64, 256, 0, stream>>>(cons, rules, s_consT, packed);
    k_fs<<<NB, 256, 0, stream>>>(x, centers, widths, packed, out_nfs, nfs_bf, out_xe, sx);
    k_gemm<<<dim3(NB / 128, KSPLIT), 256, 0, stream>>>(nfs_bf, s_consT, part);
    k_out<<<(NB * NC + 255) / 256, 256, 0, stream>>>(part, sx, out_rule);
}

// Round 3
// 33.344 us; speedup vs baseline: 1.1523x; 1.1523x over previous
//
#include <hip/hip_runtime.h>
#include <hip/hip_bf16.h>

typedef __attribute__((ext_vector_type(8))) short short8;
typedef __attribute__((ext_vector_type(4))) short short4v;
typedef __attribute__((ext_vector_type(4))) float floatx4;
typedef __attribute__((ext_vector_type(4))) unsigned int uintx4;
typedef unsigned int u32;
typedef unsigned short u16;

#define NB 1024
#define ND 16
#define NM 4
#define NR 4096
#define NC 64
#define EPSF 1e-9f
#define KSPLIT 8

__device__ inline u16 f2bf(float f) {
    u32 u;
    __builtin_memcpy(&u, &f, 4);
    u32 lsb = (u >> 16) & 1;
    u += 0x7fffu + lsb;   // round-to-nearest-even
    return (u16)(u >> 16);
}

// ---- Kernel A: s_consT[c][r] = bf16(sum_j cons[r,j,c]); pack rules (2b x 16d) ----
// 256 blocks x 16 rules each -> all CUs active (was 64 blocks: per-CU BW bound).
__global__ __launch_bounds__(256) void k_prep(const float* __restrict__ cons,
                                              const int* __restrict__ rules,
                                              u16* __restrict__ s_consT,
                                              u32* __restrict__ packed) {
    __shared__ u16 tile[16][68];  // [r_local][c], padded
    int rbase = blockIdx.x * 16;
    int tid = threadIdx.x;
    int c = tid & 63;
    {
        int rr = tid >> 6;  // 0..3, loop over 4
#pragma unroll
        for (int it = 0; it < 4; ++it, rr += 4) {
            const float* p = cons + (size_t)(rbase + rr) * (ND + 1) * NC + c;
            float s = 0.f;
#pragma unroll
            for (int j = 0; j < ND + 1; ++j) s += p[j * NC];
            tile[rr][c] = f2bf(s);
        }
    }
    if (tid < 16) {
        const int* q = rules + (size_t)(rbase + tid) * ND;
        u32 pk = 0;
#pragma unroll
        for (int d = 0; d < ND; ++d) pk |= ((u32)(q[d] & 3)) << (2 * d);
        packed[rbase + tid] = pk;
    }
    __syncthreads();
    // transposed write: thread t -> col cc = t>>2, rows (t&3)*4 .. +3, 8B store
    {
        int cc = tid >> 2;
        int r0 = (tid & 3) * 4;
        short4v v;
#pragma unroll
        for (int e = 0; e < 4; ++e) v[e] = (short)tile[r0 + e][cc];
        *(short4v*)(s_consT + (size_t)cc * NR + rbase + r0) = v;
    }
}

// ---- Kernel B: per-b firing strengths + normalization; fp32 nfs out + bf16 copy ----
__global__ __launch_bounds__(256) void k_fs(const float* __restrict__ x,
                                            const float* __restrict__ centers,
                                            const float* __restrict__ widths,
                                            const u32* __restrict__ packed,
                                            float* __restrict__ out_nfs,
                                            u16* __restrict__ nfs_bf,
                                            float* __restrict__ out_xe,
                                            float* __restrict__ sx) {
    __shared__ float xv[16];
    __shared__ float mftab[64];
    __shared__ float gtab[1024];
    __shared__ float fsbuf[4096];
    __shared__ float wred[4];
    __shared__ float s_inv;
    int b = blockIdx.x;
    int tid = threadIdx.x;
    if (tid < 16) {
        float raw = x[b * 16 + tid];
        xv[tid] = raw;
        out_xe[b * 17 + tid] = raw;
    }
    if (tid == 16) out_xe[b * 17 + 16] = 1.0f;
    __syncthreads();
    if (tid < 64) {
        float diff = xv[tid >> 2] - centers[tid];
        float w = widths[tid];
        mftab[tid] = __expf(-diff * diff / (2.f * w * w)) + EPSF;
    }
    if (tid == 0) {
        float s = 1.f;
        for (int i = 0; i < 16; ++i) s += xv[i];
        sx[b] = s;
    }
    __syncthreads();
    // 4 groups of 4 dims, 256-entry product tables
    for (int idx = tid; idx < 1024; idx += 256) {
        int g = idx >> 8, i = idx & 255;
        const float* mf = mftab + g * 16;
        gtab[idx] = mf[0 + (i & 3)] * mf[4 + ((i >> 2) & 3)] *
                    mf[8 + ((i >> 4) & 3)] * mf[12 + ((i >> 6) & 3)];
    }
    __syncthreads();
    float lsum = 0.f;
#pragma unroll
    for (int it = 0; it < 4; ++it) {
        int r = it * 1024 + tid * 4;
        uintx4 p = *(const uintx4*)(packed + r);
        floatx4 f;
#pragma unroll
        for (int e = 0; e < 4; ++e) {
            u32 pk = p[e];
            f[e] = gtab[pk & 255] * gtab[256 + ((pk >> 8) & 255)] *
                   gtab[512 + ((pk >> 16) & 255)] * gtab[768 + (pk >> 24)];
            lsum += f[e];
        }
        *(floatx4*)(fsbuf + r) = f;
    }
    for (int off = 32; off; off >>= 1) lsum += __shfl_down(lsum, off, 64);
    if ((tid & 63) == 0) wred[tid >> 6] = lsum;
    __syncthreads();
    if (tid == 0) s_inv = 1.f / (wred[0] + wred[1] + wred[2] + wred[3] + EPSF);
    __syncthreads();
    float inv = s_inv;
    float* on = out_nfs + (size_t)b * NR;
    u16* ob = nfs_bf + (size_t)b * NR;
#pragma unroll
    for (int it = 0; it < 4; ++it) {
        int r = it * 1024 + tid * 4;
        floatx4 f = *(const floatx4*)(fsbuf + r);
        floatx4 v;
        short4v bv;
#pragma unroll
        for (int e = 0; e < 4; ++e) {
            v[e] = f[e] * inv;
            bv[e] = (short)f2bf(v[e]);
        }
        *(floatx4*)(on + r) = v;
        *(short4v*)(ob + r) = bv;
    }
}

// ---- Kernel C: nfs_bf (B x R) @ s_cons (R x C), K-split, no LDS (all LLC-resident) ----
__global__ __launch_bounds__(256) void k_gemm(const u16* __restrict__ nfs,
                                              const u16* __restrict__ s_consT,
                                              float* __restrict__ part) {
    int rt = blockIdx.x;  // 16 row tiles of 64
    int ks = blockIdx.y;  // 8 k-splits of 512
    int tid = threadIdx.x;
    int wid = tid >> 6, lane = tid & 63;
    int arow = rt * 64 + wid * 16 + (lane & 15);
    int klane = (lane >> 4) * 8;
    int kbase = ks * (NR / KSPLIT);
    const u16* aptr = nfs + (size_t)arow * NR + kbase + klane;
    const u16* bptr = s_consT + (size_t)(lane & 15) * NR + kbase + klane;
    floatx4 acc[4] = {};
#pragma unroll 4
    for (int t = 0; t < 16; ++t) {
        short8 af = *(const short8*)(aptr + t * 32);
#pragma unroll
        for (int cb = 0; cb < 4; ++cb) {
            short8 bf = *(const short8*)(bptr + (size_t)cb * 16 * NR + t * 32);
            acc[cb] = __builtin_amdgcn_mfma_f32_16x16x32_bf16(af, bf, acc[cb], 0, 0, 0);
        }
    }
    float* po = part + (size_t)ks * (NB * NC);
#pragma unroll
    for (int cb = 0; cb < 4; ++cb)
#pragma unroll
        for (int reg = 0; reg < 4; ++reg) {
            int row = rt * 64 + wid * 16 + (lane >> 4) * 4 + reg;
            int col = cb * 16 + (lane & 15);
            po[(size_t)row * NC + col] = acc[cb][reg];
        }
}

// ---- Kernel D: reduce K-splits, scale by s_x, emit fp32 ----
__global__ __launch_bounds__(256) void k_out(const float* __restrict__ part,
                                             const float* __restrict__ sx,
                                             float* __restrict__ out0) {
    int t = blockIdx.x * 256 + threadIdx.x;
    if (t >= NB * NC) return;
    float a = 0.f;
#pragma unroll
    for (int ks = 0; ks < KSPLIT; ++ks) a += part[(size_t)ks * (NB * NC) + t];
    out0[t] = a * sx[t >> 6];
}

extern "C" void kernel_launch(void* const* d_in, const int* in_sizes, int n_in,
                              void* d_out, int out_size, void* d_ws, size_t ws_size,
                              hipStream_t stream) {
    const float* x = (const float*)d_in[0];
    const float* centers = (const float*)d_in[1];
    const float* widths = (const float*)d_in[2];
    const float* cons = (const float*)d_in[3];
    const int* rules = (const int*)d_in[4];

    float* out = (float*)d_out;
    float* out_rule = out;                        // [1024,64]
    float* out_nfs = out + NB * NC;               // [1024,4096]
    float* out_xe = out + NB * NC + NB * NR;      // [1024,17]

    char* ws = (char*)d_ws;
    u16* s_consT = (u16*)ws;                                   // 512 KB
    u32* packed = (u32*)(ws + (512 << 10));                    // 16 KB
    float* sx = (float*)(ws + (512 << 10) + (16 << 10));       // 4 KB
    float* part = (float*)(ws + (512 << 10) + (20 << 10));     // 2 MB
    u16* nfs_bf = (u16*)(ws + (512 << 10) + (20 << 10) + (NB * NC * KSPLIT * 4));  // 8 MB

    k_prep<<<NR / 16, 256, 0, stream>>>(cons, rules, s_consT, packed);
    k_fs<<<NB, 256, 0, stream>>>(x, centers, widths, packed, out_nfs, nfs_bf, out_xe, sx);
    k_gemm<<<dim3(NB / 64, KSPLIT), 256, 0, stream>>>(nfs_bf, s_consT, part);
    k_out<<<(NB * NC + 255) / 256, 256, 0, stream>>>(part, sx, out_rule);
}

// Round 4
// 32.024 us; speedup vs baseline: 1.1998x; 1.0412x over previous
//
#include <hip/hip_runtime.h>
#include <hip/hip_bf16.h>

typedef __attribute__((ext_vector_type(8))) short short8;
typedef __attribute__((ext_vector_type(4))) short short4v;
typedef __attribute__((ext_vector_type(4))) float floatx4;
typedef __attribute__((ext_vector_type(4))) unsigned int uintx4;
typedef unsigned int u32;
typedef unsigned short u16;

#define NB 1024
#define ND 16
#define NM 4
#define NR 4096
#define NC 64
#define EPSF 1e-9f
#define KSPLIT 16

__device__ inline u16 f2bf(float f) {
    u32 u;
    __builtin_memcpy(&u, &f, 4);
    u32 lsb = (u >> 16) & 1;
    u += 0x7fffu + lsb;   // round-to-nearest-even
    return (u16)(u >> 16);
}

// ---- Kernel A: s_consT[c][r] = bf16(sum_j cons[r,j,c]); pack rules; zero out_rule ----
__global__ __launch_bounds__(256) void k_prep(const float* __restrict__ cons,
                                              const int* __restrict__ rules,
                                              u16* __restrict__ s_consT,
                                              u32* __restrict__ packed,
                                              float* __restrict__ out_rule) {
    __shared__ u16 tile[16][68];  // [r_local][c], padded
    int rbase = blockIdx.x * 16;
    int tid = threadIdx.x;
    int c = tid & 63;
    out_rule[blockIdx.x * 256 + tid] = 0.f;  // 256 blocks x 256 = 65536 = NB*NC
    {
        int rr = tid >> 6;  // 0..3
#pragma unroll
        for (int it = 0; it < 4; ++it, rr += 4) {
            const float* p = cons + (size_t)(rbase + rr) * (ND + 1) * NC + c;
            float s = 0.f;
#pragma unroll
            for (int j = 0; j < ND + 1; ++j) s += p[j * NC];
            tile[rr][c] = f2bf(s);
        }
    }
    if (tid < 16) {
        const int* q = rules + (size_t)(rbase + tid) * ND;
        u32 pk = 0;
#pragma unroll
        for (int d = 0; d < ND; ++d) pk |= ((u32)(q[d] & 3)) << (2 * d);
        packed[rbase + tid] = pk;
    }
    __syncthreads();
    {
        int cc = tid >> 2;
        int r0 = (tid & 3) * 4;
        short4v v;
#pragma unroll
        for (int e = 0; e < 4; ++e) v[e] = (short)tile[r0 + e][cc];
        *(short4v*)(s_consT + (size_t)cc * NR + rbase + r0) = v;
    }
}

// ---- Kernel B: per-b firing strengths + normalization; fp32 nfs in registers ----
__global__ __launch_bounds__(256) void k_fs(const float* __restrict__ x,
                                            const float* __restrict__ centers,
                                            const float* __restrict__ widths,
                                            const u32* __restrict__ packed,
                                            float* __restrict__ out_nfs,
                                            float* __restrict__ out_xe,
                                            float* __restrict__ sx) {
    __shared__ float xv[16];
    __shared__ float mftab[64];
    __shared__ float gtab[1024];
    __shared__ float wred[4];
    __shared__ float s_inv;
    int b = blockIdx.x;
    int tid = threadIdx.x;
    if (tid < 16) {
        float raw = x[b * 16 + tid];
        xv[tid] = raw;
        out_xe[b * 17 + tid] = raw;
    }
    if (tid == 16) out_xe[b * 17 + 16] = 1.0f;
    __syncthreads();
    if (tid < 64) {
        float diff = xv[tid >> 2] - centers[tid];
        float w = widths[tid];
        mftab[tid] = __expf(-diff * diff / (2.f * w * w)) + EPSF;
    }
    if (tid == 0) {
        float s = 1.f;
        for (int i = 0; i < 16; ++i) s += xv[i];
        sx[b] = s;
    }
    __syncthreads();
    // 4 groups of 4 dims, 256-entry product tables
    for (int idx = tid; idx < 1024; idx += 256) {
        int g = idx >> 8, i = idx & 255;
        const float* mf = mftab + g * 16;
        gtab[idx] = mf[0 + (i & 3)] * mf[4 + ((i >> 2) & 3)] *
                    mf[8 + ((i >> 4) & 3)] * mf[12 + ((i >> 6) & 3)];
    }
    __syncthreads();
    floatx4 f[4];
    float lsum = 0.f;
#pragma unroll
    for (int it = 0; it < 4; ++it) {
        int r = it * 1024 + tid * 4;
        uintx4 p = *(const uintx4*)(packed + r);
#pragma unroll
        for (int e = 0; e < 4; ++e) {
            u32 pk = p[e];
            f[it][e] = gtab[pk & 255] * gtab[256 + ((pk >> 8) & 255)] *
                       gtab[512 + ((pk >> 16) & 255)] * gtab[768 + (pk >> 24)];
            lsum += f[it][e];
        }
    }
    for (int off = 32; off; off >>= 1) lsum += __shfl_down(lsum, off, 64);
    if ((tid & 63) == 0) wred[tid >> 6] = lsum;
    __syncthreads();
    if (tid == 0) s_inv = 1.f / (wred[0] + wred[1] + wred[2] + wred[3] + EPSF);
    __syncthreads();
    float inv = s_inv;
    float* on = out_nfs + (size_t)b * NR;
#pragma unroll
    for (int it = 0; it < 4; ++it) {
        int r = it * 1024 + tid * 4;
        floatx4 v;
#pragma unroll
        for (int e = 0; e < 4; ++e) v[e] = f[it][e] * inv;
        *(floatx4*)(on + r) = v;
    }
}

// ---- Kernel C: fp32 nfs (B x R) -> bf16 in-reg, MFMA vs s_consT, atomic sx-scaled out ----
__global__ __launch_bounds__(256) void k_gemm(const float* __restrict__ nfs,
                                              const u16* __restrict__ s_consT,
                                              const float* __restrict__ sx,
                                              float* __restrict__ out_rule) {
    int rt = blockIdx.x;  // 16 row tiles of 64
    int ks = blockIdx.y;  // 16 k-splits of 256
    int tid = threadIdx.x;
    int wid = tid >> 6, lane = tid & 63;
    int arow = rt * 64 + wid * 16 + (lane & 15);
    int kbase = ks * (NR / KSPLIT) + (lane >> 4) * 8;
    const float* aptr = nfs + (size_t)arow * NR + kbase;
    const u16* bptr = s_consT + (size_t)(lane & 15) * NR + kbase;
    floatx4 acc[4] = {};
#pragma unroll
    for (int t = 0; t < (NR / KSPLIT) / 32; ++t) {  // 8 steps
        floatx4 alo = *(const floatx4*)(aptr + t * 32);
        floatx4 ahi = *(const floatx4*)(aptr + t * 32 + 4);
        short8 af;
#pragma unroll
        for (int e = 0; e < 4; ++e) {
            af[e] = (short)f2bf(alo[e]);
            af[e + 4] = (short)f2bf(ahi[e]);
        }
#pragma unroll
        for (int cb = 0; cb < 4; ++cb) {
            short8 bf = *(const short8*)(bptr + (size_t)cb * 16 * NR + t * 32);
            acc[cb] = __builtin_amdgcn_mfma_f32_16x16x32_bf16(af, bf, acc[cb], 0, 0, 0);
        }
    }
    int orow0 = rt * 64 + wid * 16 + (lane >> 4) * 4;
    float s4[4];
#pragma unroll
    for (int reg = 0; reg < 4; ++reg) s4[reg] = sx[orow0 + reg];
#pragma unroll
    for (int cb = 0; cb < 4; ++cb)
#pragma unroll
        for (int reg = 0; reg < 4; ++reg) {
            int col = cb * 16 + (lane & 15);
            atomicAdd(out_rule + (size_t)(orow0 + reg) * NC + col, acc[cb][reg] * s4[reg]);
        }
}

extern "C" void kernel_launch(void* const* d_in, const int* in_sizes, int n_in,
                              void* d_out, int out_size, void* d_ws, size_t ws_size,
                              hipStream_t stream) {
    const float* x = (const float*)d_in[0];
    const float* centers = (const float*)d_in[1];
    const float* widths = (const float*)d_in[2];
    const float* cons = (const float*)d_in[3];
    const int* rules = (const int*)d_in[4];

    float* out = (float*)d_out;
    float* out_rule = out;                        // [1024,64]
    float* out_nfs = out + NB * NC;               // [1024,4096]
    float* out_xe = out + NB * NC + NB * NR;      // [1024,17]

    char* ws = (char*)d_ws;
    u16* s_consT = (u16*)ws;                                   // 512 KB
    u32* packed = (u32*)(ws + (512 << 10));                    // 16 KB
    float* sx = (float*)(ws + (512 << 10) + (16 << 10));       // 4 KB

    k_prep<<<NR / 16, 256, 0, stream>>>(cons, rules, s_consT, packed, out_rule);
    k_fs<<<NB, 256, 0, stream>>>(x, centers, widths, packed, out_nfs, out_xe, sx);
    k_gemm<<<dim3(16, KSPLIT), 256, 0, stream>>>(out_nfs, s_consT, sx, out_rule);
}